// Round 12
// baseline (27.037 us; speedup 1.0000x reference)
//
#include <hip/hip_runtime.h>

// Problem geometry (fixed by reference setup_inputs)
#define B   4
#define D   48
#define H   128
#define W   240
#define H4  512   // 4*H
#define W4  960   // 4*W
#define HW  (H * W)
#define NPIX (B * HW)      // 122880
#define DO8 (D / 8)        // 6 d-slices per lane octant

// Kernel 1: top-2 soft-argmax, float4 x 8-way-d-split edition.
// Lane group of 8 owns 4 consecutive pixels; lane octant o holds d in
// [6o, 6o+6). 6 float4 loads/thread (coalesced), streaming top-2 per pixel,
// 3-step shfl_xor butterfly merge (lower lane = lower d range -> lowest-index
// tie-break preserved). 245760 threads -> 960 blocks (restores R4's TLP,
// which R11's 480-block variant lost) with 4x fewer VMEM issues than scalar.
__global__ void __launch_bounds__(256)
topk_softargmax_kernel(const float* __restrict__ cost, float* __restrict__ disp4) {
    int gid  = blockIdx.x * 256 + threadIdx.x;     // 0 .. 2*NPIX-1
    int o    = gid & 7;                            // d-octant
    int pix0 = (gid >> 3) * 4;                     // base pixel of the quad
    int b    = pix0 / HW;
    int rem  = pix0 - b * HW;
    const float* p = cost + (size_t)b * (D * HW) + (size_t)(o * DO8) * HW + rem;

    float4 vv[DO8];
    #pragma unroll
    for (int j = 0; j < DO8; ++j)
        vv[j] = *reinterpret_cast<const float4*>(p + (size_t)j * HW);

    float v1[4], v2[4]; int i1[4], i2[4];
    #pragma unroll
    for (int c = 0; c < 4; ++c) { v1[c] = -INFINITY; v2[c] = -INFINITY; i1[c] = 0; i2[c] = 0; }

    #pragma unroll
    for (int j = 0; j < DO8; ++j) {
        int d = o * DO8 + j;
        float xs[4] = { vv[j].x, vv[j].y, vv[j].z, vv[j].w };
        #pragma unroll
        for (int c = 0; c < 4; ++c) {
            float x = xs[c];
            if (x > v1[c])      { v2[c] = v1[c]; i2[c] = i1[c]; v1[c] = x; i1[c] = d; }
            else if (x > v2[c]) { v2[c] = x;  i2[c] = d; }
        }
    }

    // butterfly merge across the 8-lane group (masks 1, 2, 4)
    #pragma unroll
    for (int step = 1; step <= 4; step <<= 1) {
        bool lower = (o & step) == 0;              // my list covers the lower d range
        #pragma unroll
        for (int c = 0; c < 4; ++c) {
            float pv1 = __shfl_xor(v1[c], step);
            int   pi1 = __shfl_xor(i1[c], step);
            float pv2 = __shfl_xor(v2[c], step);
            int   pi2 = __shfl_xor(i2[c], step);
            float av1, av2, bv1, bv2; int ai1, ai2, bi1, bi2;
            if (lower) { av1=v1[c]; ai1=i1[c]; av2=v2[c]; ai2=i2[c]; bv1=pv1; bi1=pi1; bv2=pv2; bi2=pi2; }
            else       { av1=pv1;   ai1=pi1;   av2=pv2;   ai2=pi2;   bv1=v1[c]; bi1=i1[c]; bv2=v2[c]; bi2=i2[c]; }
            if (bv1 > av1) {        // top1 from high-d list
                v1[c] = bv1; i1[c] = bi1;
                if (av1 >= bv2) { v2[c] = av1; i2[c] = ai1; } else { v2[c] = bv2; i2[c] = bi2; }
            } else {                // ties -> low index
                v1[c] = av1; i1[c] = ai1;
                if (av2 >= bv1) { v2[c] = av2; i2[c] = ai2; } else { v2[c] = bv1; i2[c] = bi1; }
            }
        }
    }

    if (o == 0) {
        float4 r;
        { float e = expf(v2[0]-v1[0]); r.x = ((float)i1[0] + (float)i2[0]*e) / (1.0f+e); }
        { float e = expf(v2[1]-v1[1]); r.y = ((float)i1[1] + (float)i2[1]*e) / (1.0f+e); }
        { float e = expf(v2[2]-v1[2]); r.z = ((float)i1[2] + (float)i2[2]*e) / (1.0f+e); }
        { float e = expf(v2[3]-v1[3]); r.w = ((float)i1[3] + (float)i2[3]*e) / (1.0f+e); }
        *reinterpret_cast<float4*>(disp4 + pix0) = r;
    }
}

// Kernel 2: R4's proven upfeat (warm marginal ~12.5us = at-rate for 79 MB).
__global__ void __launch_bounds__(256)
upfeat_kernel(const float* __restrict__ disp4, const float* __restrict__ spg,
              float* __restrict__ out) {
    int t = blockIdx.x * blockDim.x + threadIdx.x;
    const int nt = B * H4 * (W4 / 4);
    if (t >= nt) return;

    int xs  = t % W;
    int tmp = t / W;
    int Y   = tmp % H4;
    int b   = tmp / H4;
    int y   = Y >> 2;

    float dv[9];
    const float* dp = disp4 + (size_t)b * HW;
    #pragma unroll
    for (int dy = 0; dy < 3; ++dy) {
        int yy = y + dy - 1;
        #pragma unroll
        for (int dx = 0; dx < 3; ++dx) {
            int xx = xs + dx - 1;
            dv[dy * 3 + dx] = (yy >= 0 && yy < H && xx >= 0 && xx < W)
                              ? dp[yy * W + xx] : 0.0f;
        }
    }

    const float* sp = spg + (((size_t)b * 9) * H4 + Y) * W4 + 4 * xs;
    float4 acc = make_float4(0.f, 0.f, 0.f, 0.f);
    #pragma unroll
    for (int k = 0; k < 9; ++k) {
        float4 s = *reinterpret_cast<const float4*>(sp + (size_t)k * (H4 * W4));
        float  d = dv[k];
        acc.x += d * s.x; acc.y += d * s.y; acc.z += d * s.z; acc.w += d * s.w;
    }
    acc.x *= 4.f; acc.y *= 4.f; acc.z *= 4.f; acc.w *= 4.f;

    *reinterpret_cast<float4*>(out + ((size_t)b * H4 + Y) * W4 + 4 * xs) = acc;
}

extern "C" void kernel_launch(void* const* d_in, const int* in_sizes, int n_in,
                              void* d_out, int out_size, void* d_ws, size_t ws_size,
                              hipStream_t stream) {
    const float* cost = (const float*)d_in[0];   // [B,1,D,H,W]
    const float* spg  = (const float*)d_in[1];   // [B,9,H4,W4]
    float* outp  = (float*)d_out;                // [B,H4,W4]
    float* disp4 = (float*)d_ws;                 // [B,H,W] scratch (491 KB)

    {
        const int n = NPIX * 2;                  // 245760 threads, 960 blocks
        topk_softargmax_kernel<<<(n + 255) / 256, 256, 0, stream>>>(cost, disp4);
    }
    {
        const int n = B * H4 * (W4 / 4);         // 491520 threads, 1920 blocks
        upfeat_kernel<<<(n + 255) / 256, 256, 0, stream>>>(disp4, spg, outp);
    }
}